// Round 6
// baseline (72.349 us; speedup 1.0000x reference)
//
#include <hip/hip_runtime.h>
#include <hip/hip_bf16.h>

#define SEQ    2048
#define NHEAD  16
#define RPH    512          // rows per head = B*D
#define BM     128
#define BK     64
#define NTH    256

#define WSTRIDE 2184        // elems per wrev copy; 2184 % 64 == 8 (uniform slots)
#define WCOP_E  2216        // wbase staging: guard(8)+data(2048)+pad(160)
#define TOT_E   (WCOP_E + 8 * WSTRIDE)   // 19688 elems = 39376 B

typedef float  f32x4  __attribute__((ext_vector_type(4)));
typedef __bf16 bf16x8 __attribute__((ext_vector_type(8)));

struct PF { float4 v0, v1, v2, v3, v4, v5, v6, v7; };

__device__ __forceinline__ unsigned f2bf(float f) {
    union { __hip_bfloat16 h; unsigned short u; } cv;
    cv.h = __float2bfloat16(f);
    return (unsigned)cv.u;
}

__device__ __forceinline__ bf16x8 pack8(float4 a, float4 b) {
    bf16x8 r;
    r[0] = (__bf16)a.x; r[1] = (__bf16)a.y; r[2] = (__bf16)a.z; r[3] = (__bf16)a.w;
    r[4] = (__bf16)b.x; r[5] = (__bf16)b.y; r[6] = (__bf16)b.z; r[7] = (__bf16)b.w;
    return r;
}

#define MFMA16(a, b, c) __builtin_amdgcn_mfma_f32_16x16x32_bf16((a), (b), (c), 0, 0, 0)

// Load chunk CH's four A fragments (fp32) for this lane: rows (rbw+col_low,
// rbw+16+col_low), cols s0 + {8kq, 8kq+32} .. +7  (32B contiguous per lane).
#define LOADA(P, CH)                                                          \
  { const float* gA_ = Ar0 + (size_t)(CH) * BK;                               \
    P.v0 = *(const float4*)gA_;                                               \
    P.v1 = *(const float4*)(gA_ + 4);                                         \
    P.v2 = *(const float4*)(gA_ + 32);                                        \
    P.v3 = *(const float4*)(gA_ + 36);                                        \
    const float* gB_ = Ar1 + (size_t)(CH) * BK;                               \
    P.v4 = *(const float4*)gB_;                                               \
    P.v5 = *(const float4*)(gB_ + 4);                                         \
    P.v6 = *(const float4*)(gB_ + 32);                                        \
    P.v7 = *(const float4*)(gB_ + 36); }

// One K=32 step: in-reg A frags, B from pair window bw[] (dedup j = 2ks - c).
#define KSTEP2(AF0, AF1, BASE)                                                \
  { acc[0][0] = MFMA16(AF0, bw[(BASE)    ], acc[0][0]);                       \
    acc[1][0] = MFMA16(AF1, bw[(BASE)    ], acc[1][0]);                       \
    acc[0][1] = MFMA16(AF0, bw[(BASE) - 1], acc[0][1]);                       \
    acc[1][1] = MFMA16(AF1, bw[(BASE) - 1], acc[1][1]);                       \
    acc[0][2] = MFMA16(AF0, bw[(BASE) - 2], acc[0][2]);                       \
    acc[1][2] = MFMA16(AF1, bw[(BASE) - 2], acc[1][2]);                       \
    acc[0][3] = MFMA16(AF0, bw[(BASE) - 3], acc[0][3]);                       \
    acc[1][3] = MFMA16(AF1, bw[(BASE) - 3], acc[1][3]);                       \
    acc[0][4] = MFMA16(AF0, bw[(BASE) - 4], acc[0][4]);                       \
    acc[1][4] = MFMA16(AF1, bw[(BASE) - 4], acc[1][4]);                       \
    acc[0][5] = MFMA16(AF0, bw[(BASE) - 5], acc[0][5]);                       \
    acc[1][5] = MFMA16(AF1, bw[(BASE) - 5], acc[1][5]);                       \
    acc[0][6] = MFMA16(AF0, bw[(BASE) - 6], acc[0][6]);                       \
    acc[1][6] = MFMA16(AF1, bw[(BASE) - 6], acc[1][6]);                       \
    acc[0][7] = MFMA16(AF0, bw[(BASE) - 7], acc[0][7]);                       \
    acc[1][7] = MFMA16(AF1, bw[(BASE) - 7], acc[1][7]); }

__global__ __launch_bounds__(NTH, 2) void mixer_kernel(
    const float* __restrict__ x, const float* __restrict__ wgt,
    const float* __restrict__ bias, float* __restrict__ out)
{
    __shared__ unsigned short smem[TOT_E] __attribute__((aligned(16)));
    unsigned short* wc = smem + WCOP_E;        // 8 shifted reversed-w copies

    const int tid  = threadIdx.x;
    const int lane = tid & 63;
    const int wv   = tid >> 6;

    // ---- block decode: 512 blocks, uniform 34 chunks each ----
    const int bid  = blockIdx.x;               // 0..511
    const int m    = (bid & 7) + 8 * ((bid >> 3) & 1);
    const int rt   = (bid >> 4) & 3;           // row tile 0..3
    const int pr   = bid >> 6;                 // 0..7
    const int ct_hi = 15 - pr;
    const int ct_lo = pr;

    const float* Xb = x   + (size_t)(m * RPH + rt * BM) * SEQ;
    float*       Ob = out + (size_t)(m * RPH + rt * BM) * SEQ;
    const float* wr = wgt  + m * SEQ;
    const float* br = bias + m * SEQ;

    // ---- per-lane MFMA constants ----
    const int col_low = lane & 15;
    const int kq      = lane >> 4;
    const int rbw     = 32 * wv;               // wave owns rows [rbw, rbw+32)
    const int cpy     = (col_low + 1) & 7;     // alignment class -> copy id
    const int BcBase  = cpy * WSTRIDE + cpy + 2047 - col_low + 8 * kq;

    // A-fragment base pointers (direct global, no LDS round-trip)
    const float* Ar0 = Xb + (size_t)(rbw + col_low) * SEQ + 8 * kq;
    const float* Ar1 = Ar0 + 16 * (size_t)SEQ;

    // ---- issue chunk-0/1 A prefetch immediately (hides under prologue) ----
    PF pfA, pfB;
    LOADA(pfA, 0);
    LOADA(pfB, 1);

    // ---- phase 1: reversed bf16 weights: wbase[i] = bf16(w[2047-i]) ----
    {
        const int t8 = tid * 8;                // 0..2040
        const float* g = wr + (2040 - t8);
        float4 lo = *(const float4*)g;
        float4 hi = *(const float4*)(g + 4);
        uint4 v;
        v.x = f2bf(hi.w) | (f2bf(hi.z) << 16);
        v.y = f2bf(hi.y) | (f2bf(hi.x) << 16);
        v.z = f2bf(lo.w) | (f2bf(lo.z) << 16);
        v.w = f2bf(lo.y) | (f2bf(lo.x) << 16);
        *(uint4*)(smem + 8 + t8) = v;
        if (tid < 21) {                        // guard (8) + pad (160)
            uint4 z = {0u, 0u, 0u, 0u};
            unsigned short* dst = (tid == 0) ? smem
                                 : smem + 8 + 2048 + (tid - 1) * 8;
            *(uint4*)dst = z;
        }
    }
    __syncthreads();

    // ---- phase 2: 8 shifted copies, vectorized: copy_c[i] = wbase[i-c] ----
    #pragma unroll
    for (int c = 0; c < 8; ++c) {
        for (int grp = tid; grp < WSTRIDE / 8; grp += NTH) {
            const int i = grp * 8;
            uint4 g0 = *(const uint4*)(smem + 8 + i - 8);
            uint4 g1 = *(const uint4*)(smem + 8 + i);
            unsigned d[9] = {g0.x, g0.y, g0.z, g0.w,
                             g1.x, g1.y, g1.z, g1.w, 0u};
            const int qd = (16 - 2 * c) >> 2;
            uint4 o;
            if (c & 1) {
                o.x = (d[qd]     >> 16) | (d[qd + 1] << 16);
                o.y = (d[qd + 1] >> 16) | (d[qd + 2] << 16);
                o.z = (d[qd + 2] >> 16) | (d[qd + 3] << 16);
                o.w = (d[qd + 3] >> 16) | (d[qd + 4] << 16);
            } else {
                o.x = d[qd];     o.y = d[qd + 1];
                o.z = d[qd + 2]; o.w = d[qd + 3];
            }
            *(uint4*)(wc + c * WSTRIDE + i) = o;
        }
    }
    __syncthreads();
    // LAST barrier: wcop read-only below; A never touches LDS.

    // ---- two col tiles per block: ct_hi then ct_lo (34 chunks total) ----
    #pragma unroll
    for (int half = 0; half < 2; ++half) {
        const int ct  = half ? ct_lo : ct_hi;
        const int t0  = ct << 7;
        const int nch = 2 * (ct + 1);
        const int Bc0 = BcBase - t0;

        if (half) { LOADA(pfA, 0); LOADA(pfB, 1); }

        f32x4 acc[2][8] = {};
        for (int ch = 0; ch < nch; ch += 2) {
            // B pair window: 14 distinct words (vs 32 uses)
            bf16x8 bw[14];
            const unsigned short* bpp = wc + (Bc0 + 64 * ch - 112);
            #pragma unroll
            for (int i = 0; i < 14; ++i)
                bw[i] = *(const bf16x8*)(bpp + 16 * i);

            // chunk ch: cvt A to bf16 (frees pfA), issue ch+2 loads, MFMA
            bf16x8 a00 = pack8(pfA.v0, pfA.v1);
            bf16x8 a01 = pack8(pfA.v2, pfA.v3);
            bf16x8 a10 = pack8(pfA.v4, pfA.v5);
            bf16x8 a11 = pack8(pfA.v6, pfA.v7);
            if (ch + 2 < nch) LOADA(pfA, ch + 2);
            __builtin_amdgcn_s_setprio(1);
            KSTEP2(a00, a10, 7);               // ks = 0
            KSTEP2(a01, a11, 9);               // ks = 1
            __builtin_amdgcn_s_setprio(0);

            // chunk ch+1: same with pfB
            bf16x8 b00 = pack8(pfB.v0, pfB.v1);
            bf16x8 b01 = pack8(pfB.v2, pfB.v3);
            bf16x8 b10 = pack8(pfB.v4, pfB.v5);
            bf16x8 b11 = pack8(pfB.v6, pfB.v7);
            if (ch + 3 < nch) LOADA(pfB, ch + 3);
            __builtin_amdgcn_s_setprio(1);
            KSTEP2(b00, b10, 11);              // ks = 0
            KSTEP2(b01, b11, 13);              // ks = 1
            __builtin_amdgcn_s_setprio(0);
        }

        // epilogue: C/D layout col=lane&15, row=(lane>>4)*4+reg
        #pragma unroll
        for (int c = 0; c < 8; ++c) {
            const int colg = t0 + 16 * c + col_low;
            const float bv = br[colg];
            #pragma unroll
            for (int a = 0; a < 2; ++a) {
                const int rowl = rbw + 16 * a + 4 * kq;
                #pragma unroll
                for (int r = 0; r < 4; ++r)
                    Ob[(size_t)(rowl + r) * SEQ + colg] = acc[a][c][r] + bv;
            }
        }
    }
}

extern "C" void kernel_launch(void* const* d_in, const int* in_sizes, int n_in,
                              void* d_out, int out_size, void* d_ws, size_t ws_size,
                              hipStream_t stream) {
    const float* x  = (const float*)d_in[0];
    const float* w  = (const float*)d_in[1];
    const float* bs = (const float*)d_in[2];
    float* out = (float*)d_out;
    dim3 grid(512);    // 16 heads x 4 row tiles x 8 uniform ct-pairs
    dim3 block(NTH);
    hipLaunchKernelGGL(mixer_kernel, grid, block, 0, stream, x, w, bs, out);
}

// Round 7
// 46.074 us; speedup vs baseline: 1.5703x; 1.5703x over previous
//
#include <hip/hip_runtime.h>
#include <hip/hip_bf16.h>

#define SEQ    2048
#define NHEAD  16
#define RPH    512          // rows per head = B*D
#define BM     128
#define BK     64
#define NTH    256

#define WSTRIDE 2184        // elems per wrev copy; 2184 % 64 == 8 (uniform slots)
#define ABUF_E  8192        // elems per A buffer (128 rows x 64 cols bf16)
#define WCOP_E  (2 * ABUF_E)               // wcop after the two A buffers
#define TOT_E   (WCOP_E + 8 * WSTRIDE)     // 16384 + 17472 = 33856 elems (67712 B)
// wbase staging (guard 0..7, data 8..2055, zero pad 2056..2215) aliases abuf0

typedef float  f32x4  __attribute__((ext_vector_type(4)));
typedef __bf16 bf16x8 __attribute__((ext_vector_type(8)));

struct PF { float4 v0, v1, v2, v3, v4, v5, v6, v7; };

__device__ __forceinline__ unsigned f2bf(float f) {
    union { __hip_bfloat16 h; unsigned short u; } cv;
    cv.h = __float2bfloat16(f);
    return (unsigned)cv.u;
}

__device__ __forceinline__ uint4 pack8u(float4 a, float4 b) {
    union { bf16x8 v; uint4 u; } r;
    r.v[0] = (__bf16)a.x; r.v[1] = (__bf16)a.y;
    r.v[2] = (__bf16)a.z; r.v[3] = (__bf16)a.w;
    r.v[4] = (__bf16)b.x; r.v[5] = (__bf16)b.y;
    r.v[6] = (__bf16)b.z; r.v[7] = (__bf16)b.w;
    return r.u;
}

#define MFMA16(a, b, c) __builtin_amdgcn_mfma_f32_16x16x32_bf16((a), (b), (c), 0, 0, 0)

// Load the wave-private 32x64 fp32 slice of chunk CH into P (8 float4).
#define LOADPF(P, CH)                                                         \
  { const float* g_ = Xp + (size_t)(CH) * BK;                                 \
    P.v0 = *(const float4*)g_;                                                \
    P.v1 = *(const float4*)(g_ + 4);                                          \
    P.v2 = *(const float4*)(g_ + 8 * SEQ);                                    \
    P.v3 = *(const float4*)(g_ + 8 * SEQ + 4);                                \
    P.v4 = *(const float4*)(g_ + 16 * SEQ);                                   \
    P.v5 = *(const float4*)(g_ + 16 * SEQ + 4);                               \
    P.v6 = *(const float4*)(g_ + 24 * SEQ);                                   \
    P.v7 = *(const float4*)(g_ + 24 * SEQ + 4); }

// Pack+write P into the wave-private rows of buffer AB (XOR-swizzled).
#define WRITEA(AB, P)                                                         \
  { *(uint4*)((AB) + wb0) = pack8u(P.v0, P.v1);                               \
    *(uint4*)((AB) + wb1) = pack8u(P.v2, P.v3);                               \
    *(uint4*)((AB) + wb2) = pack8u(P.v4, P.v5);                               \
    *(uint4*)((AB) + wb3) = pack8u(P.v6, P.v7); }

// Load 4 window words (16 elems apart) into slots S0..S3 of bw[16].
// Word w of pair base ch: element Bc0 + 64*ch + OFFE + 16*j.
#define WINLOAD4(CH, OFFE, S0, S1, S2, S3)                                    \
  { const unsigned short* bq_ = wcB + 64 * (CH) + (OFFE);                     \
    bw[S0] = *(const bf16x8*)(bq_);                                           \
    bw[S1] = *(const bf16x8*)(bq_ + 16);                                      \
    bw[S2] = *(const bf16x8*)(bq_ + 32);                                      \
    bw[S3] = *(const bf16x8*)(bq_ + 48); }

// One K=32 step: A frags from LDS buf ABC, B words from circular bw
// at slot (P8 + BASE - c) & 15 (all compile-time constants).
#define KSTEPW(ABC, KS, P8, BASE)                                             \
  { const int kb_ = (64 * (KS) + kq16) ^ swz;                                 \
    bf16x8 af0 = *(const bf16x8*)((ABC) + Arow0 + kb_);                       \
    bf16x8 af1 = *(const bf16x8*)((ABC) + Arow1 + kb_);                       \
    acc[0][0] = MFMA16(af0, bw[((P8)+(BASE)-0)&15], acc[0][0]);               \
    acc[1][0] = MFMA16(af1, bw[((P8)+(BASE)-0)&15], acc[1][0]);               \
    acc[0][1] = MFMA16(af0, bw[((P8)+(BASE)-1)&15], acc[0][1]);               \
    acc[1][1] = MFMA16(af1, bw[((P8)+(BASE)-1)&15], acc[1][1]);               \
    acc[0][2] = MFMA16(af0, bw[((P8)+(BASE)-2)&15], acc[0][2]);               \
    acc[1][2] = MFMA16(af1, bw[((P8)+(BASE)-2)&15], acc[1][2]);               \
    acc[0][3] = MFMA16(af0, bw[((P8)+(BASE)-3)&15], acc[0][3]);               \
    acc[1][3] = MFMA16(af1, bw[((P8)+(BASE)-3)&15], acc[1][3]);               \
    acc[0][4] = MFMA16(af0, bw[((P8)+(BASE)-4)&15], acc[0][4]);               \
    acc[1][4] = MFMA16(af1, bw[((P8)+(BASE)-4)&15], acc[1][4]);               \
    acc[0][5] = MFMA16(af0, bw[((P8)+(BASE)-5)&15], acc[0][5]);               \
    acc[1][5] = MFMA16(af1, bw[((P8)+(BASE)-5)&15], acc[1][5]);               \
    acc[0][6] = MFMA16(af0, bw[((P8)+(BASE)-6)&15], acc[0][6]);               \
    acc[1][6] = MFMA16(af1, bw[((P8)+(BASE)-6)&15], acc[1][6]);               \
    acc[0][7] = MFMA16(af0, bw[((P8)+(BASE)-7)&15], acc[0][7]);               \
    acc[1][7] = MFMA16(af1, bw[((P8)+(BASE)-7)&15], acc[1][7]); }

// One pair (chunks ch, ch+1). Slots offset P8 alternates 0/8 per pair.
// Window refills: words 8p+14..17 after chunk1 (overwrite i=0,1 + spare
// slots), words 8p+18..21 after chunk2 (overwrite i=2..5) — all consumed.
#define PAIRBODY(P8)                                                          \
  {                                                                           \
    if (ch + 2 < nch) LOADPF(pfA, ch + 2);                                    \
    WRITEA(ab1, pfB);                                                         \
    __builtin_amdgcn_s_setprio(1);                                            \
    KSTEPW(ab0, 0, P8, 7);                                                    \
    KSTEPW(ab0, 1, P8, 9);                                                    \
    __builtin_amdgcn_s_setprio(0);                                            \
    if (ch + 2 < nch)                                                         \
        WINLOAD4(ch, 112, ((P8)+14)&15, ((P8)+15)&15,                         \
                 ((P8)+16)&15, ((P8)+17)&15);                                 \
    if (ch + 3 < nch) LOADPF(pfB, ch + 3);                                    \
    if (ch + 2 < nch) WRITEA(ab0, pfA);                                       \
    __builtin_amdgcn_s_setprio(1);                                            \
    KSTEPW(ab1, 0, P8, 11);                                                   \
    KSTEPW(ab1, 1, P8, 13);                                                   \
    __builtin_amdgcn_s_setprio(0);                                            \
    if (ch + 2 < nch)                                                         \
        WINLOAD4(ch, 176, ((P8)+18)&15, ((P8)+19)&15,                         \
                 ((P8)+20)&15, ((P8)+21)&15);                                 \
  }

__global__ __launch_bounds__(NTH, 2) void mixer_kernel(
    const float* __restrict__ x, const float* __restrict__ wgt,
    const float* __restrict__ bias, float* __restrict__ out)
{
    __shared__ unsigned short smem[TOT_E] __attribute__((aligned(16)));
    char* ab0 = (char*)smem;                    // A buffer 0 (bytes)
    char* ab1 = (char*)smem + ABUF_E * 2;       // A buffer 1 (bytes)
    unsigned short* wc = smem + WCOP_E;         // 8 shifted reversed-w copies

    const int tid  = threadIdx.x;
    const int lane = tid & 63;
    const int wv   = tid >> 6;

    // ---- block decode: 512 blocks, uniform 34 chunks each ----
    const int bid  = blockIdx.x;               // 0..511
    const int m    = (bid & 7) + 8 * ((bid >> 3) & 1);
    const int rt   = (bid >> 4) & 3;           // row tile 0..3
    const int pr   = bid >> 6;                 // 0..7
    const int ct_hi = 15 - pr;
    const int ct_lo = pr;

    const float* Xb = x   + (size_t)(m * RPH + rt * BM) * SEQ;
    float*       Ob = out + (size_t)(m * RPH + rt * BM) * SEQ;
    const float* wr = wgt  + m * SEQ;
    const float* br = bias + m * SEQ;

    // ---- wave-private staging map: wave wv owns rows [32*wv, 32*wv+32) ----
    const int sr    = lane >> 3;               // 0..7
    const int sc    = (lane & 7) * 8;          // 0..56 (fp32 col)
    const int wsw   = ((lane & 7) * 16) ^ (sr << 4);
    const int rbw   = 32 * wv;
    const int wb0   = (rbw + sr)      * 128 + wsw;
    const int wb1   = (rbw + sr + 8)  * 128 + wsw;
    const int wb2   = (rbw + sr + 16) * 128 + wsw;
    const int wb3   = (rbw + sr + 24) * 128 + wsw;
    const float* Xp = Xb + (size_t)(rbw + sr) * SEQ + sc;

    // ---- issue chunk-0/1 prefetch immediately (hides under prologue) ----
    PF pfA, pfB;
    LOADPF(pfA, 0);
    LOADPF(pfB, 1);

    // ---- phase 1: reversed bf16 weights into abuf0-alias ----
    {
        const int t8 = tid * 8;                // 0..2040
        const float* g = wr + (2040 - t8);
        float4 lo = *(const float4*)g;
        float4 hi = *(const float4*)(g + 4);
        uint4 v;
        v.x = f2bf(hi.w) | (f2bf(hi.z) << 16);
        v.y = f2bf(hi.y) | (f2bf(hi.x) << 16);
        v.z = f2bf(lo.w) | (f2bf(lo.z) << 16);
        v.w = f2bf(lo.y) | (f2bf(lo.x) << 16);
        *(uint4*)(smem + 8 + t8) = v;
        if (tid < 21) {                        // guard (8) + pad (160)
            uint4 z = {0u, 0u, 0u, 0u};
            unsigned short* dst = (tid == 0) ? smem
                                 : smem + 8 + 2048 + (tid - 1) * 8;
            *(uint4*)dst = z;
        }
    }
    __syncthreads();

    // ---- phase 2: 8 shifted copies, vectorized: copy_c[i] = wbase[i-c] ----
    #pragma unroll
    for (int c = 0; c < 8; ++c) {
        for (int grp = tid; grp < WSTRIDE / 8; grp += NTH) {
            const int i = grp * 8;
            uint4 g0 = *(const uint4*)(smem + 8 + i - 8);
            uint4 g1 = *(const uint4*)(smem + 8 + i);
            unsigned d[9] = {g0.x, g0.y, g0.z, g0.w,
                             g1.x, g1.y, g1.z, g1.w, 0u};
            const int qd = (16 - 2 * c) >> 2;
            uint4 o;
            if (c & 1) {
                o.x = (d[qd]     >> 16) | (d[qd + 1] << 16);
                o.y = (d[qd + 1] >> 16) | (d[qd + 2] << 16);
                o.z = (d[qd + 2] >> 16) | (d[qd + 3] << 16);
                o.w = (d[qd + 3] >> 16) | (d[qd + 4] << 16);
            } else {
                o.x = d[qd];     o.y = d[qd + 1];
                o.z = d[qd + 2]; o.w = d[qd + 3];
            }
            *(uint4*)(wc + c * WSTRIDE + i) = o;
        }
    }
    __syncthreads();
    // LAST barrier in the kernel: wcop read-only, A slices wave-private.

    // ---- per-lane MFMA constants ----
    const int col_low = lane & 15;
    const int kq      = lane >> 4;
    const int kq16    = kq * 16;
    const int swz     = (col_low & 7) << 4;
    const int cpy     = (col_low + 1) & 7;     // alignment class -> copy id
    const int BcBase  = cpy * WSTRIDE + cpy + 2047 - col_low + 8 * kq;
    const int Arow0   = (rbw      + col_low) * 128;
    const int Arow1   = (rbw + 16 + col_low) * 128;

    // ---- two col tiles per block: ct_hi then ct_lo (34 chunks total) ----
    #pragma unroll
    for (int half = 0; half < 2; ++half) {
        const int ct  = half ? ct_lo : ct_hi;
        const int t0  = ct << 7;
        const int nch = 2 * (ct + 1);
        const unsigned short* wcB = wc + (BcBase - t0);  // element Bc0 base

        if (half) { LOADPF(pfA, 0); LOADPF(pfB, 1); }
        WRITEA(ab0, pfA);

        // circular B window: slot(w) = w & 15; prologue = words 0..13
        bf16x8 bw[16];
        {
            const unsigned short* bq_ = wcB - 112;
            #pragma unroll
            for (int i = 0; i < 14; ++i)
                bw[i] = *(const bf16x8*)(bq_ + 16 * i);
        }

        f32x4 acc[2][8] = {};
        int ch = 0;
        for (;;) {
            PAIRBODY(0);
            ch += 2; if (ch >= nch) break;
            PAIRBODY(8);
            ch += 2; if (ch >= nch) break;
        }

        // epilogue: C/D layout col=lane&15, row=(lane>>4)*4+reg
        #pragma unroll
        for (int c = 0; c < 8; ++c) {
            const int colg = t0 + 16 * c + col_low;
            const float bv = br[colg];
            #pragma unroll
            for (int a = 0; a < 2; ++a) {
                const int rowl = rbw + 16 * a + 4 * kq;
                #pragma unroll
                for (int r = 0; r < 4; ++r)
                    Ob[(size_t)(rowl + r) * SEQ + colg] = acc[a][c][r] + bv;
            }
        }
    }
}

extern "C" void kernel_launch(void* const* d_in, const int* in_sizes, int n_in,
                              void* d_out, int out_size, void* d_ws, size_t ws_size,
                              hipStream_t stream) {
    const float* x  = (const float*)d_in[0];
    const float* w  = (const float*)d_in[1];
    const float* bs = (const float*)d_in[2];
    float* out = (float*)d_out;
    dim3 grid(512);    // 16 heads x 4 row tiles x 8 uniform ct-pairs
    dim3 block(NTH);
    hipLaunchKernelGGL(mixer_kernel, grid, block, 0, stream, x, w, bs, out);
}